// Round 3
// baseline (836.396 us; speedup 1.0000x reference)
//
#include <hip/hip_runtime.h>
#include <hip/hip_bf16.h>

#define TS 20
#define DNUM 128
#define HH 256
#define NWORDS 16384
#define WPB 16                      // words per group
#define GRPS 8                      // groups per block -> 128 words/block
#define NBLK 256                    // == CU count; bid>>7 = dir

typedef __attribute__((ext_vector_type(8))) short s8v;
typedef __attribute__((ext_vector_type(4))) float f4v;

#define L2E 1.4426950408889634f

__device__ __forceinline__ unsigned short bf16_rne(float f) {
  union { float f; unsigned u; } x; x.f = f;
  unsigned r = x.u + 0x7fffu + ((x.u >> 16) & 1u);
  return (unsigned short)(r >> 16);
}

// tab4[dir][c][u] = float4(-L2E*xz, -L2E*xr, 2*L2E*xh, 0), xg = b_in + emb[c]@Wk
__global__ void build_tab4(const float* __restrict__ emb,
                           const float* __restrict__ wkF, const float* __restrict__ bF,
                           const float* __restrict__ wkB, const float* __restrict__ bB,
                           float* __restrict__ tab4) {
  int gid = blockIdx.x * 256 + threadIdx.x;
  if (gid >= 2 * 129 * 768) return;
  int dir = gid / (129 * 768);
  int rem = gid - dir * (129 * 768);
  int c = rem / 768, j = rem - (rem / 768) * 768;
  int g = j >> 8, u = j & 255;
  const float* Wk = dir ? wkB : wkF;
  const float* bb = dir ? bB : bF;
  float s = bb[j];                       // b[0] row = input bias
  const float* er = emb + c * DNUM;
  #pragma unroll 4
  for (int d = 0; d < DNUM; ++d) s = fmaf(er[d], Wk[d * 768 + j], s);
  s *= (g == 2) ? (2.f * L2E) : (-L2E);
  tab4[((((size_t)dir * 129) + c) * 256 + u) * 4 + g] = s;
}

// Pack Wr into bf16 MFMA-B-fragment order (verified), pre-scaled per gate:
// gates z,r: *-L2E ; gate h: *2*L2E.
__global__ void pack_wr(const float* __restrict__ wrF, const float* __restrict__ wrB,
                        uint4* __restrict__ wp) {
  int gid = blockIdx.x * 256 + threadIdx.x;
  if (gid >= 2 * 48 * 8 * 64) return;
  int dir = gid / (48 * 8 * 64);
  int rem = gid - dir * (48 * 8 * 64);
  int ct = rem / (8 * 64);
  int kk = (rem / 64) & 7;
  int lane = rem & 63;
  const float* Wr = dir ? wrB : wrF;
  int n = ct * 16 + (lane & 15);
  int k0 = kk * 32 + (lane >> 4) * 8;
  const float sc = (ct >> 4) == 2 ? (2.f * L2E) : (-L2E);
  union { unsigned short v[8]; uint4 q; } u;
  #pragma unroll
  for (int e = 0; e < 8; ++e) u.v[e] = bf16_rne(sc * Wr[(k0 + e) * 768 + n]);
  wp[gid] = u.q;
}

// Persistent GRU: 256 blocks (1/CU), 1024 threads. Block = 1 direction x 128
// words, processed as 8 sequential groups of 16. Wave = 16 words x 16 units x
// 3 gates; full Wr slice (24 uint4 = 96 VGPR) persists in registers for the
// whole kernel. Inner loop: LDS h (bf16, dbuf) -> MFMA -> gates -> LDS write.
__global__ __launch_bounds__(1024, 4) void gru_main(
    const int* __restrict__ chars, const float* __restrict__ tab4,
    const uint4* __restrict__ wrp, const float* __restrict__ bf_,
    const float* __restrict__ bb_, float* __restrict__ out) {
  const int bid = blockIdx.x;
  const int dir = bid >> 7;            // 128 blocks per direction
  const int wslot = bid & 127;
  const float4* table = (const float4*)tab4 + (size_t)dir * 129 * 256;
  const uint4* WP = wrp + dir * (48 * 8 * 64);
  const float* brec = (dir ? bb_ : bf_) + 768;   // b[1] = recurrent bias

  const int tid = threadIdx.x;
  const int w = tid >> 6, lane = tid & 63;
  const int lr = lane >> 4, lc = lane & 15;
  const int u = w * 16 + lc;           // this wave's unit-tile

  __shared__ unsigned short hbf[2][WPB][HH + 8];   // 528B row: ~2-way banks only
  __shared__ int sch[WPB * TS];

  // Persistent recurrent-weight fragments: 3 gates x 8 k-slices, 96 VGPRs.
  uint4 Bz[8], Brr[8], Bh[8];
  #pragma unroll
  for (int kk = 0; kk < 8; ++kk) {
    Bz[kk]  = WP[((0 * 16 + w) * 8 + kk) * 64 + lane];
    Brr[kk] = WP[((1 * 16 + w) * 8 + kk) * 64 + lane];
    Bh[kk]  = WP[((2 * 16 + w) * 8 + kk) * 64 + lane];
  }

  const float br0 = -L2E * brec[0 * 256 + u];
  const float br1 = -L2E * brec[1 * 256 + u];
  const float br2 = 2.f * L2E * brec[2 * 256 + u];

  #pragma unroll 1
  for (int grp = 0; grp < GRPS; ++grp) {
    const int word0 = wslot * 128 + grp * WPB;

    // init: zero h buffer 0, load this group's chars
    for (int i = tid; i < WPB * (HH + 8) / 2; i += 1024)
      ((unsigned*)&hbf[0][0][0])[i] = 0;
    for (int i = tid; i < WPB * TS; i += 1024) sch[i] = chars[word0 * TS + i];

    float h[4];
    #pragma unroll
    for (int r = 0; r < 4; ++r) h[r] = 0.f;

    __syncthreads();

    int cur = 0;
    #pragma unroll 1
    for (int t = 0; t < TS; ++t) {
      const int ts = dir ? (TS - 1 - t) : t;   // backward: reversed sequence

      // prefetch char codes + xg rows (hide L2 latency under MFMA phase)
      int cc[4];
      float4 xg[4];
      #pragma unroll
      for (int r = 0; r < 4; ++r) cc[r] = sch[(lr * 4 + r) * TS + ts];
      #pragma unroll
      for (int r = 0; r < 4; ++r) xg[r] = table[cc[r] * 256 + u];

      f4v a0 = {br0, br0, br0, br0};
      f4v a1 = {br1, br1, br1, br1};
      f4v a2 = {br2, br2, br2, br2};

      #pragma unroll
      for (int kk = 0; kk < 8; ++kk) {
        const uint4 av = *(const uint4*)&hbf[cur][lc][kk * 32 + lr * 8];
        const s8v aa = __builtin_bit_cast(s8v, av);
        a0 = __builtin_amdgcn_mfma_f32_16x16x32_bf16(aa, __builtin_bit_cast(s8v, Bz[kk]),  a0, 0, 0, 0);
        a1 = __builtin_amdgcn_mfma_f32_16x16x32_bf16(aa, __builtin_bit_cast(s8v, Brr[kk]), a1, 0, 0, 0);
        a2 = __builtin_amdgcn_mfma_f32_16x16x32_bf16(aa, __builtin_bit_cast(s8v, Bh[kk]),  a2, 0, 0, 0);
      }

      const int nxt = cur ^ 1;
      #pragma unroll
      for (int r = 0; r < 4; ++r) {
        const int lw = lr * 4 + r;             // C/D row = word
        const float z  = __builtin_amdgcn_rcpf(1.f + __builtin_amdgcn_exp2f(xg[r].x + a0[r]));
        const float rr = __builtin_amdgcn_rcpf(1.f + __builtin_amdgcn_exp2f(xg[r].y + a1[r]));
        const float hc = fmaf(-2.f, __builtin_amdgcn_rcpf(
            1.f + __builtin_amdgcn_exp2f(fmaf(rr, a2[r], xg[r].z))), 1.f);
        const float hp = h[r];
        float hn = fmaf(1.f - z, hc - hp, hp);
        hn = (cc[r] != 0) ? hn : hp;           // masked step: pass-through
        h[r] = hn;
        hbf[nxt][lw][u] = bf16_rne(hn);
      }
      __syncthreads();
      cur = nxt;
    }

    // store this group's outputs
    #pragma unroll
    for (int r = 0; r < 4; ++r) {
      const int lw = lr * 4 + r;
      out[(size_t)(word0 + lw) * 512 + dir * 256 + u] = h[r];
    }
    __syncthreads();   // hbf reuse hazard vs next group's zero-init
  }
}

extern "C" void kernel_launch(void* const* d_in, const int* in_sizes, int n_in,
                              void* d_out, int out_size, void* d_ws, size_t ws_size,
                              hipStream_t stream) {
  const int* chars = (const int*)d_in[0];
  const float* emb = (const float*)d_in[1];
  const float* wkF = (const float*)d_in[2];
  const float* wrF = (const float*)d_in[3];
  const float* bF  = (const float*)d_in[4];
  const float* wkB = (const float*)d_in[5];
  const float* wrB = (const float*)d_in[6];
  const float* bB  = (const float*)d_in[7];
  float* outp = (float*)d_out;

  float* tab4 = (float*)d_ws;                               // 2*129*256*16B
  uint4* wrp = (uint4*)((char*)d_ws + 2 * 129 * 256 * 16);  // 2*48*8*64*16B

  build_tab4<<<(2 * 129 * 768 + 255) / 256, 256, 0, stream>>>(emb, wkF, bF, wkB, bB, tab4);
  pack_wr<<<(2 * 48 * 8 * 64 + 255) / 256, 256, 0, stream>>>(wrF, wrB, wrp);
  gru_main<<<NBLK, 1024, 0, stream>>>(chars, tab4, wrp, bF, bB, outp);
}

// Round 4
// 328.648 us; speedup vs baseline: 2.5450x; 2.5450x over previous
//
#include <hip/hip_runtime.h>
#include <hip/hip_bf16.h>

#define TS 20
#define DNUM 128
#define HH 256
#define NWORDS 16384
#define WPB 16                      // words per group (m=1)
#define GRPS 8                      // groups per block -> 128 words/block
#define NBLK 256                    // 1 block/CU; bid>>7 = dir

typedef __attribute__((ext_vector_type(8))) short s8v;
typedef __attribute__((ext_vector_type(4))) float f4v;

#define L2E 1.4426950408889634f

__device__ __forceinline__ unsigned short bf16_rne(float f) {
  union { float f; unsigned u; } x; x.f = f;
  unsigned r = x.u + 0x7fffu + ((x.u >> 16) & 1u);
  return (unsigned short)(r >> 16);
}

// tab4[dir][c][u] = float4(-L2E*xz, -L2E*xr, 2*L2E*xh, 0), xg = b_in + emb[c]@Wk
__global__ void build_tab4(const float* __restrict__ emb,
                           const float* __restrict__ wkF, const float* __restrict__ bF,
                           const float* __restrict__ wkB, const float* __restrict__ bB,
                           float* __restrict__ tab4) {
  int gid = blockIdx.x * 256 + threadIdx.x;
  if (gid >= 2 * 129 * 768) return;
  int dir = gid / (129 * 768);
  int rem = gid - dir * (129 * 768);
  int c = rem / 768, j = rem - (rem / 768) * 768;
  int g = j >> 8, u = j & 255;
  const float* Wk = dir ? wkB : wkF;
  const float* bb = dir ? bB : bF;
  float s = bb[j];                       // b[0] row = input bias
  const float* er = emb + c * DNUM;
  #pragma unroll 4
  for (int d = 0; d < DNUM; ++d) s = fmaf(er[d], Wk[d * 768 + j], s);
  s *= (g == 2) ? (2.f * L2E) : (-L2E);
  tab4[((((size_t)dir * 129) + c) * 256 + u) * 4 + g] = s;
}

// Pack Wr into bf16 MFMA-B-fragment order (verified), pre-scaled per gate:
// gates z,r: *-L2E ; gate h: *2*L2E.
__global__ void pack_wr(const float* __restrict__ wrF, const float* __restrict__ wrB,
                        uint4* __restrict__ wp) {
  int gid = blockIdx.x * 256 + threadIdx.x;
  if (gid >= 2 * 48 * 8 * 64) return;
  int dir = gid / (48 * 8 * 64);
  int rem = gid - dir * (48 * 8 * 64);
  int ct = rem / (8 * 64);
  int kk = (rem / 64) & 7;
  int lane = rem & 63;
  const float* Wr = dir ? wrB : wrF;
  int n = ct * 16 + (lane & 15);
  int k0 = kk * 32 + (lane >> 4) * 8;
  const float sc = (ct >> 4) == 2 ? (2.f * L2E) : (-L2E);
  union { unsigned short v[8]; uint4 q; } u;
  #pragma unroll
  for (int e = 0; e < 8; ++e) u.v[e] = bf16_rne(sc * Wr[(k0 + e) * 768 + n]);
  wp[gid] = u.q;
}

// Persistent GRU: 256 blocks (1/CU), 1024 threads, wave = 1 unit-tile x 3
// gates, 16 words/step. Register budget engineered under the 128/wave cap:
// z,r weights in 64 VGPRs; h-gate weights (128KB) staged ONCE into LDS.
__global__ __launch_bounds__(1024, 4) void gru_main(
    const int* __restrict__ chars, const float* __restrict__ tab4,
    const uint4* __restrict__ wrp, const float* __restrict__ bf_,
    const float* __restrict__ bb_, float* __restrict__ out) {
  const int bid = blockIdx.x;
  const int dir = bid >> 7;            // 128 blocks per direction
  const int wslot = bid & 127;
  const float4* table = (const float4*)tab4 + (size_t)dir * 129 * 256;
  const uint4* WP = wrp + dir * (48 * 8 * 64);
  const float* brec = (dir ? bb_ : bf_) + 768;   // b[1] = recurrent bias

  const int tid = threadIdx.x;
  const int w = tid >> 6, lane = tid & 63;
  const int lr = lane >> 4, lc = lane & 15;
  const int u = w * 16 + lc;           // this wave's unit-tile

  __shared__ unsigned short hbf[2][WPB][HH + 8];   // 16.9 KB, dbuf h state
  __shared__ int sch[WPB * TS];                    // 1.3 KB
  __shared__ uint4 bhl[16 * 8 * 64];               // 128 KB h-gate weights

  // Stage h-gate weight fragments into LDS once (WP index 16384 + i).
  for (int i = tid; i < 16 * 8 * 64; i += 1024) bhl[i] = WP[16384 + i];

  // z,r gate weights persist in registers: 16 uint4 = 64 VGPRs.
  uint4 Bz[8], Brr[8];
  #pragma unroll
  for (int kk = 0; kk < 8; ++kk) {
    Bz[kk]  = WP[((0 * 16 + w) * 8 + kk) * 64 + lane];
    Brr[kk] = WP[((1 * 16 + w) * 8 + kk) * 64 + lane];
  }

  const float br0 = -L2E * brec[0 * 256 + u];
  const float br1 = -L2E * brec[1 * 256 + u];
  const float br2 = 2.f * L2E * brec[2 * 256 + u];

  #pragma unroll 1
  for (int grp = 0; grp < GRPS; ++grp) {
    const int word0 = wslot * 128 + grp * WPB;

    // zero h buffer 0, load this group's chars
    for (int i = tid; i < WPB * (HH + 8) / 2; i += 1024)
      ((unsigned*)&hbf[0][0][0])[i] = 0;
    for (int i = tid; i < WPB * TS; i += 1024) sch[i] = chars[word0 * TS + i];

    float h[4];
    #pragma unroll
    for (int r = 0; r < 4; ++r) h[r] = 0.f;

    __syncthreads();

    #pragma unroll 1
    for (int t = 0; t < TS; ++t) {
      const int ts = dir ? (TS - 1 - t) : t;   // backward: reversed sequence
      const int cur = t & 1;

      // prefetch char codes + xg rows (L2 latency hides under MFMA phase)
      int cc[4];
      float4 xg[4];
      #pragma unroll
      for (int r = 0; r < 4; ++r) cc[r] = sch[(lr * 4 + r) * TS + ts];
      #pragma unroll
      for (int r = 0; r < 4; ++r) xg[r] = table[cc[r] * 256 + u];

      f4v a0 = {br0, br0, br0, br0};
      f4v a1 = {br1, br1, br1, br1};
      f4v a2 = {br2, br2, br2, br2};

      #pragma unroll
      for (int kk = 0; kk < 8; ++kk) {
        const uint4 av = *(const uint4*)&hbf[cur][lc][kk * 32 + lr * 8];
        const uint4 bh = bhl[(w * 8 + kk) * 64 + lane];
        const s8v aa = __builtin_bit_cast(s8v, av);
        a0 = __builtin_amdgcn_mfma_f32_16x16x32_bf16(aa, __builtin_bit_cast(s8v, Bz[kk]),  a0, 0, 0, 0);
        a1 = __builtin_amdgcn_mfma_f32_16x16x32_bf16(aa, __builtin_bit_cast(s8v, Brr[kk]), a1, 0, 0, 0);
        a2 = __builtin_amdgcn_mfma_f32_16x16x32_bf16(aa, __builtin_bit_cast(s8v, bh),      a2, 0, 0, 0);
      }

      #pragma unroll
      for (int r = 0; r < 4; ++r) {
        const int lw = lr * 4 + r;             // C/D row = word
        const float z  = __builtin_amdgcn_rcpf(1.f + __builtin_amdgcn_exp2f(xg[r].x + a0[r]));
        const float rr = __builtin_amdgcn_rcpf(1.f + __builtin_amdgcn_exp2f(xg[r].y + a1[r]));
        const float hc = fmaf(-2.f, __builtin_amdgcn_rcpf(
            1.f + __builtin_amdgcn_exp2f(fmaf(rr, a2[r], xg[r].z))), 1.f);
        const float hp = h[r];
        float hn = fmaf(1.f - z, hc - hp, hp);
        hn = (cc[r] != 0) ? hn : hp;           // masked step: pass-through
        h[r] = hn;
        hbf[cur ^ 1][lw][u] = bf16_rne(hn);
      }
      __syncthreads();
    }

    // store this group's outputs (from registers)
    #pragma unroll
    for (int r = 0; r < 4; ++r) {
      const int lw = lr * 4 + r;
      out[(size_t)(word0 + lw) * 512 + dir * 256 + u] = h[r];
    }
    __syncthreads();   // guard hbf/sch reuse vs next group's init
  }
}

extern "C" void kernel_launch(void* const* d_in, const int* in_sizes, int n_in,
                              void* d_out, int out_size, void* d_ws, size_t ws_size,
                              hipStream_t stream) {
  const int* chars = (const int*)d_in[0];
  const float* emb = (const float*)d_in[1];
  const float* wkF = (const float*)d_in[2];
  const float* wrF = (const float*)d_in[3];
  const float* bF  = (const float*)d_in[4];
  const float* wkB = (const float*)d_in[5];
  const float* wrB = (const float*)d_in[6];
  const float* bB  = (const float*)d_in[7];
  float* outp = (float*)d_out;

  float* tab4 = (float*)d_ws;                               // 2*129*256*16B
  uint4* wrp = (uint4*)((char*)d_ws + 2 * 129 * 256 * 16);  // 2*48*8*64*16B

  build_tab4<<<(2 * 129 * 768 + 255) / 256, 256, 0, stream>>>(emb, wkF, bF, wkB, bB, tab4);
  pack_wr<<<(2 * 48 * 8 * 64 + 255) / 256, 256, 0, stream>>>(wrF, wrB, wrp);
  gru_main<<<NBLK, 1024, 0, stream>>>(chars, tab4, wrp, bF, bB, outp);
}